// Round 1
// 795.870 us; speedup vs baseline: 1.2758x; 1.2758x over previous
//
#include <hip/hip_runtime.h>
#include <hip/hip_bf16.h>
#include <math.h>
#include <stdint.h>

// HolomorphicEqProp: B=4096, D_IN=H=1024, D_OUT=256, steps=30.
// Round-10: kill the per-step L2 writeback/invalidate.
//  rocprof R9: WRITE_SIZE = 246 MB = 30 x h (8.4 MB) -> every step's h was
//  flushed to HBM by the agent-RELEASE (buffer_wbl2 sc1) and re-fetched from
//  MALL after the agent-ACQUIRE (buffer_inv sc1 invalidates the whole XCD L2).
//  Groups are XCD-homogeneous by construction (gid&7 = XCD under round-robin
//  dispatch), so producer/consumer share one L2: exchange needs only
//  vmcnt(0)-before-signal (implied by __syncthreads) + an L1-ONLY invalidate
//  (buffer_inv sc0) on the consumer.
//  Correctness does NOT assume the placement: each block publishes
//  HW_REG_XCC_ID into a per-group mask at entry; a group uses the L2-local
//  barrier only if its mask is a power of two, else the old agent barrier.
//  (Mask protocol uses relaxed MALL reads + a release-ordered count -- no
//  acquire anywhere on the fast path, so no L2 invalidate can ever drop or
//  evict live dirty h lines.)

#define EPSF 1e-12f

typedef short bf16x8 __attribute__((ext_vector_type(8)));
typedef float f32x4 __attribute__((ext_vector_type(4)));

struct Mods { float m[32]; };

__device__ __forceinline__ unsigned short f2bf(float f) {
  union { float f; unsigned u; } v; v.f = f;
  unsigned r = v.u + 0x7FFFu + ((v.u >> 16) & 1u);  // RNE
  return (unsigned short)(r >> 16);
}

// async global->LDS (only in gemm_bt0: R1-validated pattern)
__device__ __forceinline__ void async16(const void* g, void* l) {
  __builtin_amdgcn_global_load_lds(
      (__attribute__((address_space(1))) void*)(uintptr_t)(g),
      (__attribute__((address_space(3))) void*)(unsigned)(uintptr_t)(l),
      16, 0, 0);
}

__device__ __forceinline__ float block_reduce_sum(float x) {
#pragma unroll
  for (int o = 32; o > 0; o >>= 1) x += __shfl_down(x, o, 64);
  __shared__ float sm[8];
  int lane = threadIdx.x & 63, w = threadIdx.x >> 6;
  if (lane == 0) sm[w] = x;
  __syncthreads();
  float t = 0.f;
  if (threadIdx.x == 0) {
    int nw = (int)(blockDim.x >> 6);
    for (int i = 0; i < nw; ++i) t += sm[i];
  }
  return t;
}

// ---------------- fused spectral-norm setup (fp32, exact) ----------------

__global__ void spec_col3(const float* __restrict__ Wi, const float* __restrict__ Wr,
                          const float* __restrict__ Wo, const float* __restrict__ ui,
                          const float* __restrict__ ur, const float* __restrict__ uo,
                          float* __restrict__ v) {
  int z = blockIdx.z;
  const float* W = (z == 0) ? Wi : (z == 1) ? Wr : Wo;
  const float* u = (z == 0) ? ui : (z == 1) ? ur : uo;
  int M = (z == 2) ? 256 : 1024;
  int i0 = blockIdx.y * 64;
  if (i0 >= M) return;
  int j = blockIdx.x * blockDim.x + threadIdx.x;
  float acc = 0.f;
  for (int i = i0; i < i0 + 64; ++i)
    acc += W[(size_t)i * 1024 + j] * u[i];
  atomicAdd(&v[z * 1024 + j], acc);
}

__global__ void norm3(const float* __restrict__ v, float* __restrict__ S) {
  int z = blockIdx.x;
  float acc = 0.f;
  for (int i = threadIdx.x; i < 1024; i += blockDim.x) {
    float x = v[z * 1024 + i];
    acc += x * x;
  }
  float t = block_reduce_sum(acc);
  if (threadIdx.x == 0) S[z] = t;
}

__global__ void rowsq3(const float* __restrict__ Wi, const float* __restrict__ Wr,
                       const float* __restrict__ Wo, const float* __restrict__ v,
                       float* __restrict__ S) {
  int bid = blockIdx.x;
  int z = (bid < 1024) ? 0 : (bid < 2048) ? 1 : 2;
  int row = bid - ((z == 0) ? 0 : (z == 1) ? 1024 : 2048);
  const float* W = (z == 0) ? Wi : (z == 1) ? Wr : Wo;
  const float* vv = v + z * 1024;
  float acc = 0.f;
  for (int j = threadIdx.x; j < 1024; j += blockDim.x)
    acc += W[(size_t)row * 1024 + j] * vv[j];
  float r = block_reduce_sum(acc);
  if (threadIdx.x == 0) atomicAdd(&S[3 + z], r * r);
}

__global__ void spec_finalize(float* S) {
  int m = threadIdx.x;
  if (m < 3) {
    float nv = sqrtf(S[m]);
    float inv = 1.f / (nv + EPSF);
    float u2sq = S[3 + m] * inv * inv;
    float nu = sqrtf(u2sq);
    float sigma = u2sq / (nu + EPSF);
    S[6 + m] = 1.f / sigma;
  }
}

__device__ __forceinline__ ushort4 cvt4e(float4 w, float s) {
  ushort4 r;
  r.x = f2bf(w.x * s); r.y = f2bf(w.y * s); r.z = f2bf(w.z * s); r.w = f2bf(w.w * s);
  return r;
}

__global__ void cvt_all(const float4* __restrict__ Wi, const float4* __restrict__ Wr,
                        const float4* __restrict__ Wo, const float4* __restrict__ x,
                        const float* __restrict__ S,
                        ushort4* __restrict__ oWi, ushort4* __restrict__ oWr,
                        ushort4* __restrict__ oWo, ushort4* __restrict__ ox) {
  float s6 = S[6], s7 = S[7], s8 = S[8];
  int stride = gridDim.x * blockDim.x;
  int t0 = blockIdx.x * blockDim.x + threadIdx.x;
  for (int i = t0; i < 262144; i += stride) oWi[i] = cvt4e(Wi[i], s6);
  for (int i = t0; i < 262144; i += stride) oWr[i] = cvt4e(Wr[i], s7);
  for (int i = t0; i < 65536; i += stride) oWo[i] = cvt4e(Wo[i], s8);
  for (int i = t0; i < 1048576; i += stride) ox[i] = cvt4e(x[i], 1.0f);
}

// C = A[M,K] . B[N,K]^T + bias[n], fp32 out. 64x128 tile (validated R5/R7).
__global__ __launch_bounds__(256) void gemm_bt0(
    const unsigned short* __restrict__ A, const unsigned short* __restrict__ B,
    const float* __restrict__ bias, float* __restrict__ outF,
    int M, int N, int K) {
  constexpr int BM = 64, BN = 128, BK = 32;
  __shared__ __align__(16) unsigned short As[BM * BK];
  __shared__ __align__(16) unsigned short Bs[BN * BK];
  const int tid = threadIdx.x;
  const int wave = tid >> 6, lane = tid & 63;
  const int m0 = blockIdx.x * BM, n0 = blockIdx.y * BN;
  const int wm = (wave >> 1) * 32, wn = (wave & 1) * 64;
  const int lrow = lane & 15, quad = lane >> 4;

  f32x4 acc[2][4] = {};

  for (int k0 = 0; k0 < K; k0 += BK) {
    {
      int e = tid * 8;
      int r = e >> 5, c = e & 31;
      async16(&A[(size_t)(m0 + r) * K + k0 + c], &As[e]);
#pragma unroll
      for (int inst = 0; inst < 2; ++inst) {
        int eb = inst * 2048 + tid * 8;
        int rb = eb >> 5, cb = eb & 31;
        async16(&B[(size_t)(n0 + rb) * K + k0 + cb], &Bs[eb]);
      }
    }
    __syncthreads();

    bf16x8 af[2], bfr[4];
#pragma unroll
    for (int i = 0; i < 2; ++i)
      af[i] = *(const bf16x8*)&As[(wm + i * 16 + lrow) * BK + quad * 8];
#pragma unroll
    for (int j = 0; j < 4; ++j)
      bfr[j] = *(const bf16x8*)&Bs[(wn + j * 16 + lrow) * BK + quad * 8];
#pragma unroll
    for (int i = 0; i < 2; ++i)
#pragma unroll
      for (int j = 0; j < 4; ++j)
        acc[i][j] = __builtin_amdgcn_mfma_f32_16x16x32_bf16(af[i], bfr[j], acc[i][j], 0, 0, 0);
    __syncthreads();
  }

#pragma unroll
  for (int i = 0; i < 2; ++i)
#pragma unroll
    for (int j = 0; j < 4; ++j) {
      int col = n0 + wn + j * 16 + lrow;
      float bv = bias[col];
#pragma unroll
      for (int r = 0; r < 4; ++r) {
        int row = m0 + wm + i * 16 + quad * 4 + r;
        outF[(size_t)row * N + col] = acc[i][j][r] + bv;
      }
    }
}

// ---------------- cooperative RNN ----------------

__device__ __forceinline__ void load_ws(const unsigned short* __restrict__ src,
                                        unsigned short* ws, int tid) {
  int r = tid & 63, s = tid >> 6;
  const unsigned short* p = src + (size_t)r * 1024 + s * 128;
  unsigned short* d = ws + r * 1032 + s * 128;
#pragma unroll
  for (int j = 0; j < 16; ++j)
    *(bf16x8*)(d + j * 8) = *(const bf16x8*)(p + j * 8);
}

// K-sweep with a-frag prefetch ring of depth 8; all indices compile-time.
__device__ __forceinline__ void ksweep(const unsigned short* __restrict__ a0p,
                                       const unsigned short* __restrict__ a1p,
                                       const unsigned short* ws, int lrow, int quad,
                                       f32x4 acc[2][4]) {
  bf16x8 pa0[8], pa1[8];
#pragma unroll
  for (int i = 0; i < 8; ++i) {
    pa0[i] = *(const bf16x8*)(a0p + i * 32);
    pa1[i] = *(const bf16x8*)(a1p + i * 32);
  }
#pragma unroll 1
  for (int kb = 0; kb < 32; kb += 8) {
#define PHASE(P)                                                                 \
    {                                                                            \
      const int kc = kb + P;                                                     \
      bf16x8 a0 = pa0[P], a1 = pa1[P];                                           \
      const int kn = (kc + 8) & 31;                                              \
      pa0[P] = *(const bf16x8*)(a0p + kn * 32);                                  \
      pa1[P] = *(const bf16x8*)(a1p + kn * 32);                                  \
      _Pragma("unroll")                                                          \
      for (int nf = 0; nf < 4; ++nf) {                                           \
        bf16x8 b = *(const bf16x8*)&ws[(nf * 16 + lrow) * 1032 + kc * 32 + quad * 8]; \
        acc[0][nf] = __builtin_amdgcn_mfma_f32_16x16x32_bf16(a0, b, acc[0][nf], 0, 0, 0); \
        acc[1][nf] = __builtin_amdgcn_mfma_f32_16x16x32_bf16(a1, b, acc[1][nf], 0, 0, 0); \
      }                                                                          \
    }
    PHASE(0) PHASE(1) PHASE(2) PHASE(3) PHASE(4) PHASE(5) PHASE(6) PHASE(7)
#undef PHASE
  }
}

// ---- slow/fallback barrier (agent scope, exactly the R9-validated form) ----
// Release-add publishes h device-wide (buffer_wbl2); spin uses RELAXED loads;
// ONE acquire load after success invalidates L1+L2 exactly once.
__device__ __forceinline__ void group_barrier(unsigned* ctr, unsigned target) {
  __syncthreads();  // all waves' stores issued & drained to L2
  if (threadIdx.x == 0) {
    __hip_atomic_fetch_add(ctr, 1u, __ATOMIC_RELEASE, __HIP_MEMORY_SCOPE_AGENT);
    while (__hip_atomic_load(ctr, __ATOMIC_RELAXED, __HIP_MEMORY_SCOPE_AGENT) < target)
      __builtin_amdgcn_s_sleep(2);
    (void)__hip_atomic_load(ctr, __ATOMIC_ACQUIRE, __HIP_MEMORY_SCOPE_AGENT);
  }
  __syncthreads();
}

// ---- fast barrier (group verified XCD-homogeneous): h stays in XCD L2 ----
// __syncthreads emits s_waitcnt vmcnt(0) per wave before s_barrier, which per
// the gfx9 memory model makes all h stores resident in the XCD L2 (L1 is
// write-through). Signal/poll are RELAXED agent atomics performed at MALL
// (same instruction pattern as the R9 spin -- no wbl2, no L2 inv).
// Consumer needs only an L1 invalidate: buffer_inv sc0 (L1-only; the sc0 form
// LLVM emits for tgsplit workgroup-acquire). Dirty h lines in L2 are never
// flushed or invalidated on this path.
__device__ __forceinline__ void group_barrier_l2(unsigned* ctr, unsigned target) {
  __syncthreads();  // h stores of all 8 waves now visible in XCD L2
  if (threadIdx.x == 0) {
    __hip_atomic_fetch_add(ctr, 1u, __ATOMIC_RELAXED, __HIP_MEMORY_SCOPE_AGENT);
    while (__hip_atomic_load(ctr, __ATOMIC_RELAXED, __HIP_MEMORY_SCOPE_AGENT) < target)
      __builtin_amdgcn_s_sleep(2);
    asm volatile("buffer_inv sc0" ::: "memory");  // invalidate this CU's L1 only
  }
  __syncthreads();  // (compiler emits vmcnt/lgkm drain before s_barrier)
}

// 256 blocks x 512 threads, 1 block/CU (LDS-bound). Block (mt,nt):
// M rows [mt*256,+256), N cols [nt*64,+64). Group = blocks sharing mt
// (bid&15) — closed under the h dependency, swizzled onto one XCD.
// Per-group barrier slot layout (128 B): [0]=step counter, [1]=publish
// counter, [2]=XCD mask.
__global__ __launch_bounds__(512, 1) void rnn_coop(
    const unsigned short* __restrict__ x_bf,  // [4096][1024] bf16
    const unsigned short* __restrict__ Wi,    // [1024][1024] bf16 (scaled)
    const unsigned short* __restrict__ Wr,    // [1024][1024] bf16 (scaled)
    const float* __restrict__ b_in,
    const float* __restrict__ b_rec,
    unsigned short* __restrict__ hA,
    unsigned short* __restrict__ hB,
    unsigned* __restrict__ bar,
    Mods mods) {
  __shared__ __align__(16) unsigned short ws[64 * 1032];
  __shared__ unsigned fastflag;

  const int tid = threadIdx.x;
  const int w = tid >> 6, lane = tid & 63;
  const int lrow = lane & 15, quad = lane >> 4;
  const int bid = (int)blockIdx.x;
  const int mt = (bid & 7) * 2 + ((bid >> 3) & 1);
  const int nt = bid >> 4;
  const int gid = bid & 15;
  const int m0 = mt * 256 + w * 32;
  const int n0 = nt * 64;
  unsigned* ctr = bar + gid * 32;  // 128 B per group

  // ---- publish this block's physical XCD at entry. fetch_or completes
  // before the RELEASE add is visible (release waits vmcnt(0)), so any
  // observer of count==16 sees a complete mask with plain relaxed reads.
  if (tid == 0) {
    unsigned xcc;
    asm volatile("s_getreg_b32 %0, hwreg(HW_REG_XCC_ID)" : "=s"(xcc));
    __hip_atomic_fetch_or(ctr + 2, 1u << (xcc & 15u), __ATOMIC_RELAXED,
                          __HIP_MEMORY_SCOPE_AGENT);
    __hip_atomic_fetch_add(ctr + 1, 1u, __ATOMIC_RELEASE, __HIP_MEMORY_SCOPE_AGENT);
  }

  float bin[4], brec[4];
#pragma unroll
  for (int nf = 0; nf < 4; ++nf) {
    bin[nf] = b_in[n0 + nf * 16 + lrow];
    brec[nf] = b_rec[n0 + nf * 16 + lrow];
  }

  // ---- phase A: xproj slice (registers) via Wi slice in ws ----
  load_ws(Wi + (size_t)n0 * 1024, ws, tid);
  __syncthreads();
  float xpr[2][4][4];
  {
    f32x4 xacc[2][4] = {};
    ksweep(&x_bf[(size_t)(m0 + lrow) * 1024 + quad * 8],
           &x_bf[(size_t)(m0 + 16 + lrow) * 1024 + quad * 8], ws, lrow, quad, xacc);
#pragma unroll
    for (int mf = 0; mf < 2; ++mf)
#pragma unroll
      for (int nf = 0; nf < 4; ++nf)
#pragma unroll
        for (int r = 0; r < 4; ++r)
          xpr[mf][nf][r] = xacc[mf][nf][r] + bin[nf];
  }
  __syncthreads();  // all ws (Wi) reads done

  // ---- Wr slice -> ws (resident for all steps) ----
  load_ws(Wr + (size_t)n0 * 1024, ws, tid);

  // ---- resolve group homogeneity (relaxed MALL reads only: NO acquire,
  // so no buffer_inv sc1 can ever run while dirty h lines are live) ----
  if (tid == 0) {
    while (__hip_atomic_load(ctr + 1, __ATOMIC_RELAXED, __HIP_MEMORY_SCOPE_AGENT) < 16u)
      __builtin_amdgcn_s_sleep(2);
    asm volatile("" ::: "memory");  // keep mask read after the spin
    unsigned m = __hip_atomic_load(ctr + 2, __ATOMIC_RELAXED, __HIP_MEMORY_SCOPE_AGENT);
    fastflag = ((m & (m - 1u)) == 0u) ? 1u : 0u;
  }

  // ---- t=0: h = tanh(xproj + b_rec), mod(0)=1, h_prev=0 ----
  unsigned short* cur = hA;
  unsigned short* nxt = hB;
#pragma unroll
  for (int mf = 0; mf < 2; ++mf)
#pragma unroll
    for (int nf = 0; nf < 4; ++nf)
#pragma unroll
      for (int r = 0; r < 4; ++r)
        cur[(size_t)(m0 + mf * 16 + quad * 4 + r) * 1024 + n0 + nf * 16 + lrow] =
            f2bf(tanhf(xpr[mf][nf][r] + brec[nf]));
  __syncthreads();  // ws (Wr) ready + fastflag published
  const bool fastp = (fastflag != 0u);

  // ---- steps t = 1..29 ----
#pragma unroll 1
  for (int t = 1; t < 30; ++t) {
    if (fastp) group_barrier_l2(ctr, 16u * (unsigned)t);  // h(t-1) via XCD L2
    else       group_barrier(ctr, 16u * (unsigned)t);     // device-scope fallback
    const float mod = mods.m[t];
    f32x4 acc[2][4] = {};
    ksweep(&cur[(size_t)(m0 + lrow) * 1024 + quad * 8],
           &cur[(size_t)(m0 + 16 + lrow) * 1024 + quad * 8], ws, lrow, quad, acc);
#pragma unroll
    for (int mf = 0; mf < 2; ++mf)
#pragma unroll
      for (int nf = 0; nf < 4; ++nf)
#pragma unroll
        for (int r = 0; r < 4; ++r) {
          float hv = tanhf(xpr[mf][nf][r] + (acc[mf][nf][r] + brec[nf]) * mod);
          nxt[(size_t)(m0 + mf * 16 + quad * 4 + r) * 1024 + n0 + nf * 16 + lrow] = f2bf(hv);
        }
    unsigned short* tmp = cur; cur = nxt; nxt = tmp;
  }
  // h29 ends in hB (odd number of steps after t=0); kernel-end dispatch
  // release fence writes back dirty L2 for gemm_bt0.
}

extern "C" void kernel_launch(void* const* d_in, const int* in_sizes, int n_in,
                              void* d_out, int out_size, void* d_ws, size_t ws_size,
                              hipStream_t stream) {
  const float* x     = (const float*)d_in[0];
  const float* W_in  = (const float*)d_in[1];
  const float* b_in  = (const float*)d_in[2];
  const float* W_rec = (const float*)d_in[3];
  const float* b_rec = (const float*)d_in[4];
  const float* W_out = (const float*)d_in[5];
  const float* b_out = (const float*)d_in[6];
  const float* u_in  = (const float*)d_in[7];
  const float* u_rec = (const float*)d_in[8];
  const float* u_out = (const float*)d_in[9];

  const int B = 4096, H = 1024, DOUT = 256;

  char* w = (char*)d_ws;
  float* S = (float*)w;                          // 256 floats
  float* v = S + 256;                            // 3 x 1024 floats
  unsigned* bar = (unsigned*)(w + 14336);        // 16 groups x 128 B
  unsigned short* Wi_bf = (unsigned short*)(w + (1 << 14));
  unsigned short* Wr_bf = Wi_bf + (size_t)H * H;
  unsigned short* Wo_bf = Wr_bf + (size_t)H * H;
  unsigned short* x_bf  = Wo_bf + (size_t)DOUT * H;
  unsigned short* hA = x_bf + (size_t)B * H;
  unsigned short* hB = hA + (size_t)B * H;

  hipMemsetAsync(w, 0, 1 << 14, stream);  // zero S, v, barrier counters+masks

  dim3 t256(256);
  spec_col3<<<dim3(4, 16, 3), t256, 0, stream>>>(W_in, W_rec, W_out, u_in, u_rec, u_out, v);
  norm3<<<3, t256, 0, stream>>>(v, S);
  rowsq3<<<2304, t256, 0, stream>>>(W_in, W_rec, W_out, v, S);
  spec_finalize<<<1, 64, 0, stream>>>(S);
  cvt_all<<<1024, t256, 0, stream>>>((const float4*)W_in, (const float4*)W_rec,
                                     (const float4*)W_out, (const float4*)x, S,
                                     (ushort4*)Wi_bf, (ushort4*)Wr_bf,
                                     (ushort4*)Wo_bf, (ushort4*)x_bf);

  Mods mods;
  for (int t = 0; t < 32; ++t) mods.m[t] = (float)(1.0 + 0.1 * sin(0.3 * (double)t));
  {
    void* args[] = {(void*)&x_bf, (void*)&Wi_bf, (void*)&Wr_bf, (void*)&b_in,
                    (void*)&b_rec, (void*)&hA, (void*)&hB, (void*)&bar, (void*)&mods};
    hipLaunchCooperativeKernel((const void*)rnn_coop, dim3(256), dim3(512),
                               args, 0, stream);
  }

  // out = h29 @ Wo_n^T + b_out
  gemm_bt0<<<dim3(B / 64, DOUT / 128), t256, 0, stream>>>(
      hB, Wo_bf, b_out, (float*)d_out, B, DOUT, H);
}

// Round 2
// 788.845 us; speedup vs baseline: 1.2871x; 1.0089x over previous
//
#include <hip/hip_runtime.h>
#include <hip/hip_bf16.h>
#include <math.h>
#include <stdint.h>

// HolomorphicEqProp: B=4096, D_IN=H=1024, D_OUT=256, steps=30.
// Round-11: attack the epilogue + issue stalls (R10 fixed the L2 flush).
//  rocprof R10: VALUBusy 25% / MfmaUtil 16% -> epilogue (32 scalar ushort
//  stores + 32 library tanhf + bit-twiddle f2bf per thread per step) and
//  unarbitrated 2-wave/SIMD scheduling eat ~12 us/step over the ~9 us
//  compute floor.
//  - MFMA operands SWAPPED: acc = mfma(wr_frag, h_frag). D-layout becomes
//    col=batch row (lrow), row=n-offset (quad*4+r): each lane's 4 acc regs
//    are 4 CONSECUTIVE h columns -> one 8B store per 4 values (4x fewer
//    stores, 32B segments). h memory layout unchanged (row-major), so next
//    step's a-frag reads and the final GEMM are untouched.
//  - v_cvt_pk_bf16_f32 (RNE, same rounding as f2bf) packs the bf16 pairs.
//  - tanh via 1 - 2*rcp(exp(2x)+1): ~5 VALU ops, exact at saturation.
//  - s_setprio(1) around each phase's 8-MFMA cluster (T5; b-frag ds_reads
//    hoisted ahead of the cluster).

#define EPSF 1e-12f

typedef short bf16x8 __attribute__((ext_vector_type(8)));
typedef float f32x4 __attribute__((ext_vector_type(4)));

struct Mods { float m[32]; };

__device__ __forceinline__ unsigned short f2bf(float f) {
  union { float f; unsigned u; } v; v.f = f;
  unsigned r = v.u + 0x7FFFu + ((v.u >> 16) & 1u);  // RNE
  return (unsigned short)(r >> 16);
}

// packed f32x2 -> bf16x2 (RNE), single VALU op
__device__ __forceinline__ unsigned cvt_pk_bf16(float lo, float hi) {
  unsigned r;
  asm("v_cvt_pk_bf16_f32 %0, %1, %2" : "=v"(r) : "v"(lo), "v"(hi));
  return r;
}

// tanh(x) = 1 - 2/(exp(2x)+1). __expf -> v_exp_f32; rcp -> v_rcp_f32.
// Saturates exactly (+-1); abs error ~1e-7 << bf16 eps.
__device__ __forceinline__ float tanh_fast(float x) {
  float e = __expf(2.0f * x);
  float r = __builtin_amdgcn_rcpf(e + 1.0f);
  return fmaf(-2.0f, r, 1.0f);
}

// async global->LDS (only in gemm_bt0: R1-validated pattern)
__device__ __forceinline__ void async16(const void* g, void* l) {
  __builtin_amdgcn_global_load_lds(
      (__attribute__((address_space(1))) void*)(uintptr_t)(g),
      (__attribute__((address_space(3))) void*)(unsigned)(uintptr_t)(l),
      16, 0, 0);
}

__device__ __forceinline__ float block_reduce_sum(float x) {
#pragma unroll
  for (int o = 32; o > 0; o >>= 1) x += __shfl_down(x, o, 64);
  __shared__ float sm[8];
  int lane = threadIdx.x & 63, w = threadIdx.x >> 6;
  if (lane == 0) sm[w] = x;
  __syncthreads();
  float t = 0.f;
  if (threadIdx.x == 0) {
    int nw = (int)(blockDim.x >> 6);
    for (int i = 0; i < nw; ++i) t += sm[i];
  }
  return t;
}

// ---------------- fused spectral-norm setup (fp32, exact) ----------------

__global__ void spec_col3(const float* __restrict__ Wi, const float* __restrict__ Wr,
                          const float* __restrict__ Wo, const float* __restrict__ ui,
                          const float* __restrict__ ur, const float* __restrict__ uo,
                          float* __restrict__ v) {
  int z = blockIdx.z;
  const float* W = (z == 0) ? Wi : (z == 1) ? Wr : Wo;
  const float* u = (z == 0) ? ui : (z == 1) ? ur : uo;
  int M = (z == 2) ? 256 : 1024;
  int i0 = blockIdx.y * 64;
  if (i0 >= M) return;
  int j = blockIdx.x * blockDim.x + threadIdx.x;
  float acc = 0.f;
  for (int i = i0; i < i0 + 64; ++i)
    acc += W[(size_t)i * 1024 + j] * u[i];
  atomicAdd(&v[z * 1024 + j], acc);
}

__global__ void norm3(const float* __restrict__ v, float* __restrict__ S) {
  int z = blockIdx.x;
  float acc = 0.f;
  for (int i = threadIdx.x; i < 1024; i += blockDim.x) {
    float x = v[z * 1024 + i];
    acc += x * x;
  }
  float t = block_reduce_sum(acc);
  if (threadIdx.x == 0) S[z] = t;
}

__global__ void rowsq3(const float* __restrict__ Wi, const float* __restrict__ Wr,
                       const float* __restrict__ Wo, const float* __restrict__ v,
                       float* __restrict__ S) {
  int bid = blockIdx.x;
  int z = (bid < 1024) ? 0 : (bid < 2048) ? 1 : 2;
  int row = bid - ((z == 0) ? 0 : (z == 1) ? 1024 : 2048);
  const float* W = (z == 0) ? Wi : (z == 1) ? Wr : Wo;
  const float* vv = v + z * 1024;
  float acc = 0.f;
  for (int j = threadIdx.x; j < 1024; j += blockDim.x)
    acc += W[(size_t)row * 1024 + j] * vv[j];
  float r = block_reduce_sum(acc);
  if (threadIdx.x == 0) atomicAdd(&S[3 + z], r * r);
}

__global__ void spec_finalize(float* S) {
  int m = threadIdx.x;
  if (m < 3) {
    float nv = sqrtf(S[m]);
    float inv = 1.f / (nv + EPSF);
    float u2sq = S[3 + m] * inv * inv;
    float nu = sqrtf(u2sq);
    float sigma = u2sq / (nu + EPSF);
    S[6 + m] = 1.f / sigma;
  }
}

__device__ __forceinline__ ushort4 cvt4e(float4 w, float s) {
  ushort4 r;
  r.x = f2bf(w.x * s); r.y = f2bf(w.y * s); r.z = f2bf(w.z * s); r.w = f2bf(w.w * s);
  return r;
}

__global__ void cvt_all(const float4* __restrict__ Wi, const float4* __restrict__ Wr,
                        const float4* __restrict__ Wo, const float4* __restrict__ x,
                        const float* __restrict__ S,
                        ushort4* __restrict__ oWi, ushort4* __restrict__ oWr,
                        ushort4* __restrict__ oWo, ushort4* __restrict__ ox) {
  float s6 = S[6], s7 = S[7], s8 = S[8];
  int stride = gridDim.x * blockDim.x;
  int t0 = blockIdx.x * blockDim.x + threadIdx.x;
  for (int i = t0; i < 262144; i += stride) oWi[i] = cvt4e(Wi[i], s6);
  for (int i = t0; i < 262144; i += stride) oWr[i] = cvt4e(Wr[i], s7);
  for (int i = t0; i < 65536; i += stride) oWo[i] = cvt4e(Wo[i], s8);
  for (int i = t0; i < 1048576; i += stride) ox[i] = cvt4e(x[i], 1.0f);
}

// C = A[M,K] . B[N,K]^T + bias[n], fp32 out. 64x128 tile (validated R5/R7).
__global__ __launch_bounds__(256) void gemm_bt0(
    const unsigned short* __restrict__ A, const unsigned short* __restrict__ B,
    const float* __restrict__ bias, float* __restrict__ outF,
    int M, int N, int K) {
  constexpr int BM = 64, BN = 128, BK = 32;
  __shared__ __align__(16) unsigned short As[BM * BK];
  __shared__ __align__(16) unsigned short Bs[BN * BK];
  const int tid = threadIdx.x;
  const int wave = tid >> 6, lane = tid & 63;
  const int m0 = blockIdx.x * BM, n0 = blockIdx.y * BN;
  const int wm = (wave >> 1) * 32, wn = (wave & 1) * 64;
  const int lrow = lane & 15, quad = lane >> 4;

  f32x4 acc[2][4] = {};

  for (int k0 = 0; k0 < K; k0 += BK) {
    {
      int e = tid * 8;
      int r = e >> 5, c = e & 31;
      async16(&A[(size_t)(m0 + r) * K + k0 + c], &As[e]);
#pragma unroll
      for (int inst = 0; inst < 2; ++inst) {
        int eb = inst * 2048 + tid * 8;
        int rb = eb >> 5, cb = eb & 31;
        async16(&B[(size_t)(n0 + rb) * K + k0 + cb], &Bs[eb]);
      }
    }
    __syncthreads();

    bf16x8 af[2], bfr[4];
#pragma unroll
    for (int i = 0; i < 2; ++i)
      af[i] = *(const bf16x8*)&As[(wm + i * 16 + lrow) * BK + quad * 8];
#pragma unroll
    for (int j = 0; j < 4; ++j)
      bfr[j] = *(const bf16x8*)&Bs[(wn + j * 16 + lrow) * BK + quad * 8];
#pragma unroll
    for (int i = 0; i < 2; ++i)
#pragma unroll
      for (int j = 0; j < 4; ++j)
        acc[i][j] = __builtin_amdgcn_mfma_f32_16x16x32_bf16(af[i], bfr[j], acc[i][j], 0, 0, 0);
    __syncthreads();
  }

#pragma unroll
  for (int i = 0; i < 2; ++i)
#pragma unroll
    for (int j = 0; j < 4; ++j) {
      int col = n0 + wn + j * 16 + lrow;
      float bv = bias[col];
#pragma unroll
      for (int r = 0; r < 4; ++r) {
        int row = m0 + wm + i * 16 + quad * 4 + r;
        outF[(size_t)row * N + col] = acc[i][j][r] + bv;
      }
    }
}

// ---------------- cooperative RNN ----------------

__device__ __forceinline__ void load_ws(const unsigned short* __restrict__ src,
                                        unsigned short* ws, int tid) {
  int r = tid & 63, s = tid >> 6;
  const unsigned short* p = src + (size_t)r * 1024 + s * 128;
  unsigned short* d = ws + r * 1032 + s * 128;
#pragma unroll
  for (int j = 0; j < 16; ++j)
    *(bf16x8*)(d + j * 8) = *(const bf16x8*)(p + j * 8);
}

// K-sweep, SWAPPED operand order: acc[mf][nf] = mfma(wr_frag, h_frag, acc).
// D-layout per lane: m = mf*16 + lrow (col), n = nf*16 + quad*4 + r (row).
// a-frag prefetch ring depth 8; all indices compile-time.
__device__ __forceinline__ void ksweep(const unsigned short* __restrict__ a0p,
                                       const unsigned short* __restrict__ a1p,
                                       const unsigned short* ws, int lrow, int quad,
                                       f32x4 acc[2][4]) {
  bf16x8 pa0[8], pa1[8];
#pragma unroll
  for (int i = 0; i < 8; ++i) {
    pa0[i] = *(const bf16x8*)(a0p + i * 32);
    pa1[i] = *(const bf16x8*)(a1p + i * 32);
  }
#pragma unroll 1
  for (int kb = 0; kb < 32; kb += 8) {
#define PHASE(P)                                                                 \
    {                                                                            \
      const int kc = kb + P;                                                     \
      bf16x8 a0 = pa0[P], a1 = pa1[P];                                           \
      const int kn = (kc + 8) & 31;                                              \
      pa0[P] = *(const bf16x8*)(a0p + kn * 32);                                  \
      pa1[P] = *(const bf16x8*)(a1p + kn * 32);                                  \
      bf16x8 bq0 = *(const bf16x8*)&ws[(0 * 16 + lrow) * 1032 + kc * 32 + quad * 8]; \
      bf16x8 bq1 = *(const bf16x8*)&ws[(1 * 16 + lrow) * 1032 + kc * 32 + quad * 8]; \
      bf16x8 bq2 = *(const bf16x8*)&ws[(2 * 16 + lrow) * 1032 + kc * 32 + quad * 8]; \
      bf16x8 bq3 = *(const bf16x8*)&ws[(3 * 16 + lrow) * 1032 + kc * 32 + quad * 8]; \
      __builtin_amdgcn_s_setprio(1);                                             \
      acc[0][0] = __builtin_amdgcn_mfma_f32_16x16x32_bf16(bq0, a0, acc[0][0], 0, 0, 0); \
      acc[1][0] = __builtin_amdgcn_mfma_f32_16x16x32_bf16(bq0, a1, acc[1][0], 0, 0, 0); \
      acc[0][1] = __builtin_amdgcn_mfma_f32_16x16x32_bf16(bq1, a0, acc[0][1], 0, 0, 0); \
      acc[1][1] = __builtin_amdgcn_mfma_f32_16x16x32_bf16(bq1, a1, acc[1][1], 0, 0, 0); \
      acc[0][2] = __builtin_amdgcn_mfma_f32_16x16x32_bf16(bq2, a0, acc[0][2], 0, 0, 0); \
      acc[1][2] = __builtin_amdgcn_mfma_f32_16x16x32_bf16(bq2, a1, acc[1][2], 0, 0, 0); \
      acc[0][3] = __builtin_amdgcn_mfma_f32_16x16x32_bf16(bq3, a0, acc[0][3], 0, 0, 0); \
      acc[1][3] = __builtin_amdgcn_mfma_f32_16x16x32_bf16(bq3, a1, acc[1][3], 0, 0, 0); \
      __builtin_amdgcn_s_setprio(0);                                             \
    }
    PHASE(0) PHASE(1) PHASE(2) PHASE(3) PHASE(4) PHASE(5) PHASE(6) PHASE(7)
#undef PHASE
  }
}

// ---- slow/fallback barrier (agent scope, exactly the R9-validated form) ----
__device__ __forceinline__ void group_barrier(unsigned* ctr, unsigned target) {
  __syncthreads();  // all waves' stores issued & drained to L2
  if (threadIdx.x == 0) {
    __hip_atomic_fetch_add(ctr, 1u, __ATOMIC_RELEASE, __HIP_MEMORY_SCOPE_AGENT);
    while (__hip_atomic_load(ctr, __ATOMIC_RELAXED, __HIP_MEMORY_SCOPE_AGENT) < target)
      __builtin_amdgcn_s_sleep(2);
    (void)__hip_atomic_load(ctr, __ATOMIC_ACQUIRE, __HIP_MEMORY_SCOPE_AGENT);
  }
  __syncthreads();
}

// ---- fast barrier (group verified XCD-homogeneous): h stays in XCD L2 ----
// (R10-validated: WRITE_SIZE 246 MB -> 22 MB.) Relaxed MALL signal/poll, one
// L1-only invalidate (buffer_inv sc0) on the consumer; dirty h lines in L2
// are never flushed or invalidated on this path.
__device__ __forceinline__ void group_barrier_l2(unsigned* ctr, unsigned target) {
  __syncthreads();  // h stores of all 8 waves now visible in XCD L2
  if (threadIdx.x == 0) {
    __hip_atomic_fetch_add(ctr, 1u, __ATOMIC_RELAXED, __HIP_MEMORY_SCOPE_AGENT);
    while (__hip_atomic_load(ctr, __ATOMIC_RELAXED, __HIP_MEMORY_SCOPE_AGENT) < target)
      __builtin_amdgcn_s_sleep(2);
    asm volatile("buffer_inv sc0" ::: "memory");  // invalidate this CU's L1 only
  }
  __syncthreads();
}

// 256 blocks x 512 threads, 1 block/CU (LDS-bound). Block (mt,nt):
// M rows [mt*256,+256), N cols [nt*64,+64). Group = blocks sharing mt
// (bid&15) — closed under the h dependency, swizzled onto one XCD.
// Per-group barrier slot layout (128 B): [0]=step counter, [1]=publish
// counter, [2]=XCD mask.
__global__ __launch_bounds__(512, 1) void rnn_coop(
    const unsigned short* __restrict__ x_bf,  // [4096][1024] bf16
    const unsigned short* __restrict__ Wi,    // [1024][1024] bf16 (scaled)
    const unsigned short* __restrict__ Wr,    // [1024][1024] bf16 (scaled)
    const float* __restrict__ b_in,
    const float* __restrict__ b_rec,
    unsigned short* __restrict__ hA,
    unsigned short* __restrict__ hB,
    unsigned* __restrict__ bar,
    Mods mods) {
  __shared__ __align__(16) unsigned short ws[64 * 1032];
  __shared__ unsigned fastflag;

  const int tid = threadIdx.x;
  const int w = tid >> 6, lane = tid & 63;
  const int lrow = lane & 15, quad = lane >> 4;
  const int bid = (int)blockIdx.x;
  const int mt = (bid & 7) * 2 + ((bid >> 3) & 1);
  const int nt = bid >> 4;
  const int gid = bid & 15;
  const int m0 = mt * 256 + w * 32;
  const int n0 = nt * 64;
  unsigned* ctr = bar + gid * 32;  // 128 B per group

  // ---- publish this block's physical XCD at entry (R10 protocol) ----
  if (tid == 0) {
    unsigned xcc;
    asm volatile("s_getreg_b32 %0, hwreg(HW_REG_XCC_ID)" : "=s"(xcc));
    __hip_atomic_fetch_or(ctr + 2, 1u << (xcc & 15u), __ATOMIC_RELAXED,
                          __HIP_MEMORY_SCOPE_AGENT);
    __hip_atomic_fetch_add(ctr + 1, 1u, __ATOMIC_RELEASE, __HIP_MEMORY_SCOPE_AGENT);
  }

  // per-lane biases: n = n0 + nf*16 + quad*4 + r  (swapped D-layout)
  float4 bin4[4], brec4[4];
#pragma unroll
  for (int nf = 0; nf < 4; ++nf) {
    bin4[nf] = *(const float4*)&b_in[n0 + nf * 16 + quad * 4];
    brec4[nf] = *(const float4*)&b_rec[n0 + nf * 16 + quad * 4];
  }

  // ---- phase A: xproj slice (registers) via Wi slice in ws ----
  load_ws(Wi + (size_t)n0 * 1024, ws, tid);
  __syncthreads();
  float xpr[2][4][4];  // [mf][nf][r]: m = m0+mf*16+lrow, n = n0+nf*16+quad*4+r
  {
    f32x4 xacc[2][4] = {};
    ksweep(&x_bf[(size_t)(m0 + lrow) * 1024 + quad * 8],
           &x_bf[(size_t)(m0 + 16 + lrow) * 1024 + quad * 8], ws, lrow, quad, xacc);
#pragma unroll
    for (int mf = 0; mf < 2; ++mf)
#pragma unroll
      for (int nf = 0; nf < 4; ++nf)
#pragma unroll
        for (int r = 0; r < 4; ++r)
          xpr[mf][nf][r] = xacc[mf][nf][r] + ((const float*)&bin4[nf])[r];
  }
  __syncthreads();  // all ws (Wi) reads done

  // ---- Wr slice -> ws (resident for all steps) ----
  load_ws(Wr + (size_t)n0 * 1024, ws, tid);

  // ---- resolve group homogeneity (relaxed MALL reads only; no acquire) ----
  if (tid == 0) {
    while (__hip_atomic_load(ctr + 1, __ATOMIC_RELAXED, __HIP_MEMORY_SCOPE_AGENT) < 16u)
      __builtin_amdgcn_s_sleep(2);
    asm volatile("" ::: "memory");  // keep mask read after the spin
    unsigned m = __hip_atomic_load(ctr + 2, __ATOMIC_RELAXED, __HIP_MEMORY_SCOPE_AGENT);
    fastflag = ((m & (m - 1u)) == 0u) ? 1u : 0u;
  }

  // ---- t=0: h = tanh(xproj + b_rec), mod(0)=1, h_prev=0 ----
  unsigned short* cur = hA;
  unsigned short* nxt = hB;
#pragma unroll
  for (int mf = 0; mf < 2; ++mf)
#pragma unroll
    for (int nf = 0; nf < 4; ++nf) {
      float h0 = tanh_fast(xpr[mf][nf][0] + ((const float*)&brec4[nf])[0]);
      float h1 = tanh_fast(xpr[mf][nf][1] + ((const float*)&brec4[nf])[1]);
      float h2 = tanh_fast(xpr[mf][nf][2] + ((const float*)&brec4[nf])[2]);
      float h3 = tanh_fast(xpr[mf][nf][3] + ((const float*)&brec4[nf])[3]);
      uint2 pk = {cvt_pk_bf16(h0, h1), cvt_pk_bf16(h2, h3)};
      *(uint2*)&cur[(size_t)(m0 + mf * 16 + lrow) * 1024 + n0 + nf * 16 + quad * 4] = pk;
    }
  __syncthreads();  // ws (Wr) ready + fastflag published
  const bool fastp = (fastflag != 0u);

  // ---- steps t = 1..29 ----
#pragma unroll 1
  for (int t = 1; t < 30; ++t) {
    if (fastp) group_barrier_l2(ctr, 16u * (unsigned)t);  // h(t-1) via XCD L2
    else       group_barrier(ctr, 16u * (unsigned)t);     // device-scope fallback
    const float mod = mods.m[t];
    f32x4 acc[2][4] = {};
    ksweep(&cur[(size_t)(m0 + lrow) * 1024 + quad * 8],
           &cur[(size_t)(m0 + 16 + lrow) * 1024 + quad * 8], ws, lrow, quad, acc);
#pragma unroll
    for (int mf = 0; mf < 2; ++mf)
#pragma unroll
      for (int nf = 0; nf < 4; ++nf) {
        float h0 = tanh_fast(xpr[mf][nf][0] +
                             (acc[mf][nf][0] + ((const float*)&brec4[nf])[0]) * mod);
        float h1 = tanh_fast(xpr[mf][nf][1] +
                             (acc[mf][nf][1] + ((const float*)&brec4[nf])[1]) * mod);
        float h2 = tanh_fast(xpr[mf][nf][2] +
                             (acc[mf][nf][2] + ((const float*)&brec4[nf])[2]) * mod);
        float h3 = tanh_fast(xpr[mf][nf][3] +
                             (acc[mf][nf][3] + ((const float*)&brec4[nf])[3]) * mod);
        uint2 pk = {cvt_pk_bf16(h0, h1), cvt_pk_bf16(h2, h3)};
        *(uint2*)&nxt[(size_t)(m0 + mf * 16 + lrow) * 1024 + n0 + nf * 16 + quad * 4] = pk;
      }
    unsigned short* tmp = cur; cur = nxt; nxt = tmp;
  }
  // h29 ends in hB (odd number of steps after t=0); kernel-end dispatch
  // release fence writes back dirty L2 for gemm_bt0.
}

extern "C" void kernel_launch(void* const* d_in, const int* in_sizes, int n_in,
                              void* d_out, int out_size, void* d_ws, size_t ws_size,
                              hipStream_t stream) {
  const float* x     = (const float*)d_in[0];
  const float* W_in  = (const float*)d_in[1];
  const float* b_in  = (const float*)d_in[2];
  const float* W_rec = (const float*)d_in[3];
  const float* b_rec = (const float*)d_in[4];
  const float* W_out = (const float*)d_in[5];
  const float* b_out = (const float*)d_in[6];
  const float* u_in  = (const float*)d_in[7];
  const float* u_rec = (const float*)d_in[8];
  const float* u_out = (const float*)d_in[9];

  const int B = 4096, H = 1024, DOUT = 256;

  char* w = (char*)d_ws;
  float* S = (float*)w;                          // 256 floats
  float* v = S + 256;                            // 3 x 1024 floats
  unsigned* bar = (unsigned*)(w + 14336);        // 16 groups x 128 B
  unsigned short* Wi_bf = (unsigned short*)(w + (1 << 14));
  unsigned short* Wr_bf = Wi_bf + (size_t)H * H;
  unsigned short* Wo_bf = Wr_bf + (size_t)H * H;
  unsigned short* x_bf  = Wo_bf + (size_t)DOUT * H;
  unsigned short* hA = x_bf + (size_t)B * H;
  unsigned short* hB = hA + (size_t)B * H;

  hipMemsetAsync(w, 0, 1 << 14, stream);  // zero S, v, barrier counters+masks

  dim3 t256(256);
  spec_col3<<<dim3(4, 16, 3), t256, 0, stream>>>(W_in, W_rec, W_out, u_in, u_rec, u_out, v);
  norm3<<<3, t256, 0, stream>>>(v, S);
  rowsq3<<<2304, t256, 0, stream>>>(W_in, W_rec, W_out, v, S);
  spec_finalize<<<1, 64, 0, stream>>>(S);
  cvt_all<<<1024, t256, 0, stream>>>((const float4*)W_in, (const float4*)W_rec,
                                     (const float4*)W_out, (const float4*)x, S,
                                     (ushort4*)Wi_bf, (ushort4*)Wr_bf,
                                     (ushort4*)Wo_bf, (ushort4*)x_bf);

  Mods mods;
  for (int t = 0; t < 32; ++t) mods.m[t] = (float)(1.0 + 0.1 * sin(0.3 * (double)t));
  {
    void* args[] = {(void*)&x_bf, (void*)&Wi_bf, (void*)&Wr_bf, (void*)&b_in,
                    (void*)&b_rec, (void*)&hA, (void*)&hB, (void*)&bar, (void*)&mods};
    hipLaunchCooperativeKernel((const void*)rnn_coop, dim3(256), dim3(512),
                               args, 0, stream);
  }

  // out = h29 @ Wo_n^T + b_out
  gemm_bt0<<<dim3(B / 64, DOUT / 128), t256, 0, stream>>>(
      hB, Wo_bf, b_out, (float*)d_out, B, DOUT, H);
}